// Round 7
// baseline (205.805 us; speedup 1.0000x reference)
//
#include <hip/hip_runtime.h>
#include <math.h>

// DCT encoder, separable form. kernels[k] = outer(cv_k, cu_k) with
// cv[i]=cos((2i+1)v pi/64) on ROWS (i), cu[j] on COLUMNS (j)  [meshgrid 'xy'].
// Stage1 contracts y=cols with freq f1==u; stage2 contracts x=rows with f2==v.
// R11 = R10 resubmitted verbatim (R10 hit an infra failure: "MI355X container
// failed twice" — never compiled/ran). Channel-split grid + T2-in-LDS stage-2
// (ideal WRITE=103MB) with a pinned 16-19-deep load pipeline:
//  - ALL global loads (af0/af1/T2/8R/8G then 8B) are asm volatile
//    global_load_dwordx4 -> issue order pinned, compiler cannot serialize.
//  - waits: asm "s_waitcnt vmcnt(N)" + "memory" clobber, then
//    __builtin_amdgcn_sched_barrier(0) (guide rule #18) so register-only
//    consumers cannot be hoisted above the wait. NO tied asm operands
//    (R9's "+v" vectors hit "tied indirect register inputs").
//  - af1 offset +1024 bytes (R9 had +2048, past the 2KB Cbf table).

typedef __bf16 bf16x8 __attribute__((ext_vector_type(8)));
typedef float  f32x4  __attribute__((ext_vector_type(4)));

#define PI_F 3.14159265358979323846f

// pinned global load: 16B, literal byte offset in [-4096, 4095]
#define GLOAD(dst, base, off) \
    asm volatile("global_load_dwordx4 %0, %1, off offset:%c2" \
                 : "=v"(dst) : "v"(base), "n"(off))

#define WAITVM(N) do { \
    asm volatile("s_waitcnt vmcnt(" #N ")" ::: "memory"); \
    __builtin_amdgcn_sched_barrier(0); \
} while (0)

__device__ __forceinline__ unsigned short f2bf(float f) {
    union { float f; unsigned u; } v; v.f = f;
    unsigned u = v.u;
    u += 0x7fffu + ((u >> 16) & 1u);   // round-to-nearest-even
    return (unsigned short)(u >> 16);
}

// ---- K0: cos table (bf16) + fused {k, scale} table --------------------------
// T2r layout: [(u*4 + quad)*8 + uh*4 + r] where v = uh*16 + quad*4 + r,
// so stage-2's (f1=u, quad) thread reads its 8 entries as one 64B run.
__global__ __launch_bounds__(256) void setup_kernel(const float* __restrict__ kern,
                                                    const float* __restrict__ factors,
                                                    unsigned short* __restrict__ Cbf,
                                                    int2* __restrict__ T2) {
    int k = blockIdx.x * 256 + threadIdx.x;   // 0..1023
    int i = k & 31, t = k >> 5;
    Cbf[k] = f2bf(cosf((float)((2 * i + 1) * t) * (PI_F / 64.f)));

    float k00 = kern[(size_t)k * 1024];              // cv[0]*cu[0] > 0 always
    float rv  = kern[(size_t)k * 1024 + 32] / k00;   // -> v
    float ru  = kern[(size_t)k * 1024 + 1]  / k00;   // -> u
    float cv2 = fminf(fmaxf((rv + 3.f) * 0.25f, 0.f), 1.f);
    float cu2 = fminf(fmaxf((ru + 3.f) * 0.25f, 0.f), 1.f);
    int v = __float2int_rn(acosf(sqrtf(cv2)) * (64.f / PI_F));
    int u = __float2int_rn(acosf(sqrtf(cu2)) * (64.f / PI_F));
    float s = factors[k] * (2.f / 32.f);
    int vq = (v >> 2) & 3, vh = v >> 4, vr = v & 3;
    T2[(u * 4 + vq) * 8 + vh * 4 + vr] = make_int2(k, __float_as_int(s));
}

// ---- fused kernel: one block per (b, m, c) strip of 16 DCT blocks -----------
// Stage1: T[f1][n][x] = sum_y C[f1][y] * ycbcr[c][m*32+x][n*32+y]   (MFMA, K=32)
// Stage2: out[bc][k(f2,f1)][m*16+n] = s * sum_x C[f2][x] * T[f1][n][x]
// LDS: T buffer 40 KB (row 80B = 32 bf16 + pad, f1-stride 1280B) + T2 copy 8 KB.
__global__ __launch_bounds__(512, 4) void dct_fused(const float* __restrict__ rgb,
                                                    const unsigned short* __restrict__ Cbf,
                                                    const int2* __restrict__ T2,
                                                    float* __restrict__ out) {
    __shared__ __align__(16) unsigned char Tls[32 * 1280];   // 40 KB
    __shared__ __align__(16) unsigned char T2ls[8192];       // 8 KB

    const int tid  = threadIdx.x;
    const int lane = tid & 63;
    const int w    = tid >> 6;        // wave 0..7, owns x = w*4..w*4+3
    const int quad = lane >> 4;
    const int l15  = lane & 15;
    // blockIdx decode: g = bc*16 + loc, bc = b*3 + c (c at stride 16 -> same XCD
    // for a strip's 3 channel-blocks), loc -> m with the g<->g+8 pair swizzle
    // so m=2t / 2t+1 half-lines merge to one 128B line in that XCD's L2.
    const int g    = blockIdx.x;
    const int bc   = g >> 4;          // 0..95
    const int b    = bc / 3;
    const int c    = bc - b * 3;
    const int loc  = g & 15;
    const int m    = ((loc & 7) << 1) | (loc >> 3);

    // channel conversion folded to one dot product: val = ar*R + ag*G + ab*B + ao
    float ar, ag, ab, ao;
    if (c == 0)      { ar =  0.598f;     ag =  1.174f;     ab =  0.228f;     ao = -1.f; }
    else if (c == 1) { ar = -0.337272f;  ag = -0.662136f;  ab =  0.999408f;  ao =  0.f; }
    else             { ar =  0.999626f;  ag = -0.837062f;  ab = -0.162564f;  ao =  0.f; }

    // ---- pinned 16-19-deep load pipeline -----------------------------------
    // This thread's 32 input elems: rows x = w*4+xi, cols l15*32+quad*8+e.
    const float* prow = rgb + (size_t)b * 786432
                            + (size_t)(m * 32 + w * 4) * 512
                            + (size_t)l15 * 32 + (size_t)quad * 8;
    const float* pR = prow + 768;            // rebase so offsets fit 13-bit signed
    const float* pG = prow + 262144 + 768;
    const float* pB = prow + 524288 + 768;
    const unsigned short* cbase = Cbf + l15 * 32 + quad * 8;
    const int4* t2p = (const int4*)T2 + tid;

    bf16x8 af0v, af1v;
    int4   t2q;
    f32x4  bufR[8], bufG[8], bufB[8];

    GLOAD(af0v, cbase, 0);          // A-frag rows 0..15
    GLOAD(af1v, cbase, 1024);       // A-frag rows 16..31 (+512 ushorts)
    GLOAD(t2q,  t2p,   0);          // T2 chunk for LDS staging
    // 8 R loads (byte offsets xi*2048 + h*16 - 3072)
    GLOAD(bufR[0], pR, -3072); GLOAD(bufR[1], pR, -3056);
    GLOAD(bufR[2], pR, -1024); GLOAD(bufR[3], pR, -1008);
    GLOAD(bufR[4], pR,  1024); GLOAD(bufR[5], pR,  1040);
    GLOAD(bufR[6], pR,  3072); GLOAD(bufR[7], pR,  3088);
    // 8 G loads
    GLOAD(bufG[0], pG, -3072); GLOAD(bufG[1], pG, -3056);
    GLOAD(bufG[2], pG, -1024); GLOAD(bufG[3], pG, -1008);
    GLOAD(bufG[4], pG,  1024); GLOAD(bufG[5], pG,  1040);
    GLOAD(bufG[6], pG,  3072); GLOAD(bufG[7], pG,  3088);

    // wait: af0/af1/t2/R complete (G's 8 remain in flight)
    WAITVM(8);

    // park T2 chunk into LDS (published by the pre-stage-2 barrier)
    *(int4*)(T2ls + tid * 16) = t2q;

    f32x4 acc[4][2];
#pragma unroll
    for (int xi = 0; xi < 4; ++xi)
#pragma unroll
        for (int h = 0; h < 2; ++h)
            acc[xi][h] = ar * bufR[2 * xi + h];

    // 8 B loads (issued while G still in flight; R regs now dead)
    GLOAD(bufB[0], pB, -3072); GLOAD(bufB[1], pB, -3056);
    GLOAD(bufB[2], pB, -1024); GLOAD(bufB[3], pB, -1008);
    GLOAD(bufB[4], pB,  1024); GLOAD(bufB[5], pB,  1040);
    GLOAD(bufB[6], pB,  3072); GLOAD(bufB[7], pB,  3088);

    // wait: G complete (B's 8 remain in flight)
    WAITVM(8);
#pragma unroll
    for (int xi = 0; xi < 4; ++xi)
#pragma unroll
        for (int h = 0; h < 2; ++h)
            acc[xi][h] += ag * bufG[2 * xi + h];

    // wait: B complete
    WAITVM(0);
#pragma unroll
    for (int xi = 0; xi < 4; ++xi)
#pragma unroll
        for (int h = 0; h < 2; ++h)
            acc[xi][h] += ab * bufB[2 * xi + h];

    // pack to bf16 fragments (B-operand: K=y=quad*8+e, 16-col = n=l15)
    bf16x8 fr[4];
#pragma unroll
    for (int xi = 0; xi < 4; ++xi) {
        union { bf16x8 v; unsigned short s[8]; } f;
#pragma unroll
        for (int e = 0; e < 8; ++e)
            f.s[e] = f2bf(acc[xi][e >> 2][e & 3] + ao);
        fr[xi] = f.v;
    }

    const f32x4 zero = {0.f, 0.f, 0.f, 0.f};

    // ---- stage 1b: MFMAs (transient acc) -> LDS scatter ----
#pragma unroll
    for (int fh = 0; fh < 2; ++fh) {
        f32x4 dd[4];
#pragma unroll
        for (int xi = 0; xi < 4; ++xi)
            dd[xi] = __builtin_amdgcn_mfma_f32_16x16x32_bf16(
                fh ? af1v : af0v, fr[xi], zero, 0, 0, 0);
        // scatter: T[f1][n=l15][x-chunk w], rows f1 = fh*16+quad*4+r
#pragma unroll
        for (int r = 0; r < 4; ++r) {
            const int f1 = fh * 16 + quad * 4 + r;
            ushort4 pk;
            pk.x = f2bf(dd[0][r]);
            pk.y = f2bf(dd[1][r]);
            pk.z = f2bf(dd[2][r]);
            pk.w = f2bf(dd[3][r]);
            *(ushort4*)(Tls + f1 * 1280 + l15 * 80 + w * 8) = pk;
        }
    }
    __syncthreads();   // publishes Tls and T2ls

    // ---- stage 2: LDS -> MFMA -> scattered stores (T2 from LDS: no vmcnt) ----
    const size_t obase = (size_t)bc * 262144 + (size_t)m * 16 + (size_t)l15;
#pragma unroll
    for (int i = 0; i < 4; ++i) {
        const int f1 = w * 4 + i;   // stage-1 freq == u (column freq)
        union { int4 q[4]; int2 e[8]; } tt;
        const unsigned char* tp = T2ls + (f1 * 4 + quad) * 64;
        tt.q[0] = *(const int4*)(tp);
        tt.q[1] = *(const int4*)(tp + 16);
        tt.q[2] = *(const int4*)(tp + 32);
        tt.q[3] = *(const int4*)(tp + 48);
        bf16x8 bfr = *(const bf16x8*)(Tls + f1 * 1280 + l15 * 80 + quad * 16);
#pragma unroll
        for (int uh = 0; uh < 2; ++uh) {
            f32x4 d2 = __builtin_amdgcn_mfma_f32_16x16x32_bf16(
                uh ? af1v : af0v, bfr, zero, 0, 0, 0);
#pragma unroll
            for (int r = 0; r < 4; ++r) {
                int2 ks = tt.e[uh * 4 + r];   // {k, scale} for f2 = uh*16+quad*4+r
                out[obase + (size_t)ks.x * 256] = d2[r] * __int_as_float(ks.y);
            }
        }
    }
}

extern "C" void kernel_launch(void* const* d_in, const int* in_sizes, int n_in,
                              void* d_out, int out_size, void* d_ws, size_t ws_size,
                              hipStream_t stream) {
    const float* rgb     = (const float*)d_in[0];  // (32,3,512,512)
    const float* kern    = (const float*)d_in[1];  // (1024,32,32)
    const float* factors = (const float*)d_in[2];  // (1024,)
    float* out = (float*)d_out;                    // (32,3072,16,16)

    unsigned short* Cbf = (unsigned short*)d_ws;          // 2 KB
    int2* T2 = (int2*)((char*)d_ws + 8192);               // 8 KB

    setup_kernel<<<4, 256, 0, stream>>>(kern, factors, Cbf, T2);
    dct_fused<<<1536, 512, 0, stream>>>(rgb, Cbf, T2, out);
}